// Round 1
// baseline (1098.623 us; speedup 1.0000x reference)
//
#include <hip/hip_runtime.h>
#include <stdint.h>
#include <stddef.h>

// Narrow MHA: B=8, S=1024, D=512 (per head), H=8.
// fp16 MFMA GEMMs (16x16x32_f16), fp32 softmax, fp32 outputs (out, attn).
// R5: k_attn occupancy fix. TQ 64->32 (acc[2][8]=64 f32/lane), Q A-fragments
// loaded directly from global (no Qs LDS tile), Pa = 32x1024 chunked (74 KB).
// SMEM 149,760 -> 75,008 B => 2 blocks/CU; __launch_bounds__(512,4) => 4 waves/SIMD.
typedef _Float16 h16;
typedef __attribute__((ext_vector_type(4))) _Float16 h16x4;
typedef __attribute__((ext_vector_type(8))) _Float16 h16x8;
typedef __attribute__((ext_vector_type(4))) float f32x4;

#define MFMA16(a, b, c) __builtin_amdgcn_mfma_f32_16x16x32_f16((a), (b), (c), 0, 0, 0)

#define NB 8
#define SEQ 1024
#define DEP 512
#define NH 8
#define HD 4096  /* NH*DEP */
#define BS 8192  /* NB*SEQ */

static __device__ __forceinline__ void gload_lds16(const void* g, void* l) {
  __builtin_amdgcn_global_load_lds((__attribute__((address_space(1))) void*)(g),
                                   (__attribute__((address_space(3))) void*)(l),
                                   16, 0, 0);
}

static __device__ __forceinline__ h16 f2h(float f) { return (h16)f; }

// ---------------- fused fp32 -> fp16 for q,k,v ----------------
__global__ __launch_bounds__(256) void k_conv3(const float* __restrict__ q,
                                               const float* __restrict__ k,
                                               const float* __restrict__ v,
                                               h16* __restrict__ xq, h16* __restrict__ xk,
                                               h16* __restrict__ xv) {
  int z = blockIdx.y;
  const float* in = z == 0 ? q : (z == 1 ? k : v);
  h16* out = z == 0 ? xq : (z == 1 ? xk : xv);
  int i = blockIdx.x * 256 + threadIdx.x;
  float4 f = ((const float4*)in)[i];
  h16x4 o = { f2h(f.x), f2h(f.y), f2h(f.z), f2h(f.w) };
  ((h16x4*)out)[i] = o;
}

// ---------------- mask (0/1 fp32, B*S*S floats) -> bitmask (262144 uint32) ----------------
__global__ __launch_bounds__(256) void k_maskbits(const float* __restrict__ mask,
                                                  uint32_t* __restrict__ bits) {
  int g = blockIdx.x * 256 + threadIdx.x;  // 262,144 threads, 32 floats each
  const float4* mp = (const float4*)mask + (size_t)g * 8;
  uint32_t w = 0;
#pragma unroll
  for (int u = 0; u < 8; ++u) {
    float4 f = mp[u];
    w |= (f.x != 0.f ? 1u : 0u) << (u * 4);
    w |= (f.y != 0.f ? 1u : 0u) << (u * 4 + 1);
    w |= (f.z != 0.f ? 1u : 0u) << (u * 4 + 2);
    w |= (f.w != 0.f ? 1u : 0u) << (u * 4 + 3);
  }
  bits[g] = w;
}

// ---------------- transpose + convert: in (R x C) fp32 -> out (C x R) fp16 ----------------
__global__ __launch_bounds__(256) void k_transpose(const float* __restrict__ in,
                                                   h16* __restrict__ out, int R, int C) {
  __shared__ float t[32][33];
  int c0 = blockIdx.x * 32, r0 = blockIdx.y * 32;
  int tx = threadIdx.x & 31, ty = threadIdx.x >> 5;
  for (int p = 0; p < 4; ++p)
    t[ty + p * 8][tx] = in[(size_t)(r0 + ty + p * 8) * C + c0 + tx];
  __syncthreads();
  for (int p = 0; p < 4; ++p)
    out[(size_t)(c0 + ty + p * 8) * R + r0 + tx] = f2h(t[tx][ty + p * 8]);
}

__global__ __launch_bounds__(256) void k_transpose3(const float* __restrict__ wq,
                                                    const float* __restrict__ wk,
                                                    const float* __restrict__ wv,
                                                    h16* __restrict__ oq, h16* __restrict__ ok,
                                                    h16* __restrict__ ov) {
  __shared__ float t[32][33];
  int z = blockIdx.z;
  const float* in = z == 0 ? wq : (z == 1 ? wk : wv);
  h16* out = z == 0 ? oq : (z == 1 ? ok : ov);
  const int R = 512, C = 4096;
  int c0 = blockIdx.x * 32, r0 = blockIdx.y * 32;
  int tx = threadIdx.x & 31, ty = threadIdx.x >> 5;
  for (int p = 0; p < 4; ++p)
    t[ty + p * 8][tx] = in[(size_t)(r0 + ty + p * 8) * C + c0 + tx];
  __syncthreads();
  for (int p = 0; p < 4; ++p)
    out[(size_t)(c0 + ty + p * 8) * R + r0 + tx] = f2h(t[tx][ty + p * 8]);
}

// ---------------- merged QKV projection GEMM ----------------
__global__ __launch_bounds__(256) void k_gemm_qkv(
    const h16* __restrict__ xq, const h16* __restrict__ xk, const h16* __restrict__ xv,
    const h16* __restrict__ WqT, const h16* __restrict__ WkT, const h16* __restrict__ WvT,
    const float* __restrict__ bq, const float* __restrict__ bk, const float* __restrict__ bv,
    h16* __restrict__ Qh, h16* __restrict__ Kh, h16* __restrict__ Vt) {
  __shared__ __align__(16) h16 As[128 * 64];
  __shared__ __align__(16) h16 Bs[128 * 64];
  const int z = blockIdx.z;
  const h16* A = z == 0 ? xq : (z == 1 ? xk : xv);
  const h16* Bm = z == 0 ? WqT : (z == 1 ? WkT : WvT);
  const float* bias = z == 0 ? bq : (z == 1 ? bk : bv);
  const int K = 512;
  const int tid = threadIdx.x, lane = tid & 63, wave = tid >> 6;
  const int wm = (wave >> 1) * 64, wn = (wave & 1) * 64;
  const int m0 = blockIdx.y * 128;
  const int n0 = blockIdx.x * 128;

  f32x4 acc[4][4];
  for (int i = 0; i < 4; ++i)
    for (int j = 0; j < 4; ++j) acc[i][j] = (f32x4)0.0f;

  const int lrow = lane >> 3, lcol = (lane & 7) * 8;
  const int fr = lane & 15, qd = lane >> 4;

  for (int k0 = 0; k0 < K; k0 += 64) {
    __syncthreads();
    for (int i = 0; i < 4; ++i) {
      int g = wave * 4 + i;
      int row = g * 8 + lrow;
      gload_lds16(A + (size_t)(m0 + row) * K + k0 + lcol, As + g * 512);
      gload_lds16(Bm + (size_t)(n0 + row) * K + k0 + lcol, Bs + g * 512);
    }
    __syncthreads();
    for (int kk = 0; kk < 64; kk += 32) {
      h16x8 af[4], bf[4];
      for (int i = 0; i < 4; ++i)
        af[i] = *(const h16x8*)(As + (wm + i * 16 + fr) * 64 + kk + qd * 8);
      for (int j = 0; j < 4; ++j)
        bf[j] = *(const h16x8*)(Bs + (wn + j * 16 + fr) * 64 + kk + qd * 8);
      for (int i = 0; i < 4; ++i)
        for (int j = 0; j < 4; ++j) acc[i][j] = MFMA16(af[i], bf[j], acc[i][j]);
    }
  }

  h16* Cnat = z == 0 ? Qh : Kh;
  for (int i = 0; i < 4; ++i)
    for (int j = 0; j < 4; ++j) {
      int mbase = m0 + wm + i * 16 + qd * 4;
      int ncol = n0 + wn + j * 16 + fr;
      float bv2 = bias[ncol];
      if (z < 2) {
        for (int r = 0; r < 4; ++r)
          Cnat[(size_t)(mbase + r) * HD + ncol] = f2h(acc[i][j][r] + bv2);
      } else {
        int bb = mbase >> 10, ss = mbase & 1023;
        int hh = ncol >> 9, dd = ncol & 511;
        size_t addr = ((size_t)((bb * NH + hh) * DEP + dd)) * SEQ + ss;
        h16x4 pk = { f2h(acc[i][j][0] + bv2), f2h(acc[i][j][1] + bv2),
                     f2h(acc[i][j][2] + bv2), f2h(acc[i][j][3] + bv2) };
        *(h16x4*)(Vt + addr) = pk;
      }
    }
}

// ---------------- NT GEMM (out-projection): fp32 out ----------------
template <int OUT_MODE>
__global__ __launch_bounds__(256) void k_gemm_nt(const h16* __restrict__ A,
                                                 const h16* __restrict__ Bm,
                                                 const float* __restrict__ bias,
                                                 void* __restrict__ Cout,
                                                 int M, int N, int K, int ldc) {
  __shared__ __align__(16) h16 As[128 * 64];
  __shared__ __align__(16) h16 Bs[128 * 64];
  const int tid = threadIdx.x, lane = tid & 63, wave = tid >> 6;
  const int wm = (wave >> 1) * 64, wn = (wave & 1) * 64;
  const int m0 = blockIdx.y * 128;
  const int n0 = blockIdx.x * 128;

  f32x4 acc[4][4];
  for (int i = 0; i < 4; ++i)
    for (int j = 0; j < 4; ++j) acc[i][j] = (f32x4)0.0f;

  const int lrow = lane >> 3, lcol = (lane & 7) * 8;
  const int fr = lane & 15, qd = lane >> 4;

  for (int k0 = 0; k0 < K; k0 += 64) {
    __syncthreads();
    for (int i = 0; i < 4; ++i) {
      int g = wave * 4 + i;
      int row = g * 8 + lrow;
      gload_lds16(A + (size_t)(m0 + row) * K + k0 + lcol, As + g * 512);
      gload_lds16(Bm + (size_t)(n0 + row) * K + k0 + lcol, Bs + g * 512);
    }
    __syncthreads();
    for (int kk = 0; kk < 64; kk += 32) {
      h16x8 af[4], bf[4];
      for (int i = 0; i < 4; ++i)
        af[i] = *(const h16x8*)(As + (wm + i * 16 + fr) * 64 + kk + qd * 8);
      for (int j = 0; j < 4; ++j)
        bf[j] = *(const h16x8*)(Bs + (wn + j * 16 + fr) * 64 + kk + qd * 8);
      for (int i = 0; i < 4; ++i)
        for (int j = 0; j < 4; ++j) acc[i][j] = MFMA16(af[i], bf[j], acc[i][j]);
    }
  }

  for (int i = 0; i < 4; ++i)
    for (int j = 0; j < 4; ++j) {
      int mbase = m0 + wm + i * 16 + qd * 4;
      int ncol = n0 + wn + j * 16 + fr;
      float bv2 = bias ? bias[ncol] : 0.0f;
      float* Cp = (float*)Cout;
      for (int r = 0; r < 4; ++r)
        Cp[(size_t)(mbase + r) * ldc + ncol] = acc[i][j][r] + bv2;
    }
}

// ---------------- fused attention: QK^T + mask + softmax + attn-write + PV ----------------
// grid (S/32, H, B), 512 threads (8 waves). Wave w: score cols [w*128,(w+1)*128),
// PV d-cols [w*64,(w+1)*64). Q A-fragments read directly from global (L1-shared
// across waves; no Qs tile). Phase1 LDS: Ks[1024x32 swizzled] = 64 KB.
// Phase2 LDS: Pa = P fp16, 16x 64-col chunks [32][72] (+8 pad) = 73,984 B.
// red (softmax cross-wave) above Pa. SMEM 75,008 B -> 2 blocks/CU.
#define TQ 32
#define PA_C64 2312                 /* h16 per 64-col chunk: 32*72+8 */
#define OFF_RED 73984               /* 16*PA_C64*2 */
#define CS_LD 536
#define SMEM_ATTN (OFF_RED + 1024)  /* 75,008 B */

__global__ __launch_bounds__(512, 4) void k_attn(const h16* __restrict__ Q,
                                                 const h16* __restrict__ Km,
                                                 const uint32_t* __restrict__ bits,
                                                 const h16* __restrict__ Vtg,
                                                 float* __restrict__ attn,
                                                 h16* __restrict__ ctx) {
  extern __shared__ __align__(16) char smem[];
  h16* Ks = (h16*)smem;                 // phase 1: K chunk, 1024 rows x 32 h16
  h16* Pa = (h16*)smem;                 // phase 2 (overwrites Ks)
  h16* Cs = (h16*)smem;                 // ctx staging (overwrites Pa)
  float* red = (float*)(smem + OFF_RED);

  const int tid = threadIdx.x, lane = tid & 63, wave = tid >> 6;
  const int qt = blockIdx.x, hh = blockIdx.y, b = blockIdx.z;
  const int q0 = qt * TQ;
  const int fr = lane & 15, qd = lane >> 4;
  const int ncol0 = wave * 128;
  const int bh = b * NH + hh;

  const h16* Qg = Q + (size_t)(b * SEQ + q0) * HD + hh * DEP;

  f32x4 acc[2][8];
  for (int i = 0; i < 2; ++i)
    for (int j = 0; j < 8; ++j) acc[i][j] = (f32x4)0.0f;

  for (int kc = 0; kc < 512; kc += 32) {
    __syncthreads();
    // stage K rows [wave*128, +128) x depth [kc,kc+32), slot-rotation swizzled
    for (int c = 0; c < 8; ++c) {
      int nbase = wave * 128 + c * 16;
      int n = nbase + (lane >> 2);
      int s = lane & 3;
      int sp = (s - (n >> 1)) & 3;
      gload_lds16(Km + (size_t)(b * SEQ + n) * HD + hh * DEP + kc + sp * 8,
                  Ks + nbase * 32);
    }
    // Q A-fragments straight from global (all waves read same 32 rows -> L1 hit)
    h16x8 af[2];
#pragma unroll
    for (int i = 0; i < 2; ++i)
      af[i] = *(const h16x8*)(Qg + (size_t)(i * 16 + fr) * HD + kc + qd * 8);
    __syncthreads();
#pragma unroll
    for (int j = 0; j < 8; ++j) {
      int n = ncol0 + j * 16 + fr;
      int slot = (qd + (n >> 1)) & 3;
      h16x8 bf = *(const h16x8*)(Ks + n * 32 + slot * 8);
      for (int i = 0; i < 2; ++i) acc[i][j] = MFMA16(af[i], bf, acc[i][j]);
    }
  }

  // ---- phase 1b: mask (bits) + softmax ----
  const float scale = 0.044194173824159216f;  // 1/sqrt(512)
  const uint32_t* bitp = bits + (size_t)(b * SEQ + q0) * 32 + wave * 4;
  float rmax[2][4];
#pragma unroll
  for (int i = 0; i < 2; ++i) {
    uint4 mwi[4];
    for (int r = 0; r < 4; ++r)
      mwi[r] = *(const uint4*)(bitp + (size_t)(i * 16 + qd * 4 + r) * 32);
    for (int r = 0; r < 4; ++r) rmax[i][r] = -3.4e38f;
#pragma unroll
    for (int j = 0; j < 8; ++j)
      for (int r = 0; r < 4; ++r) {
        uint32_t ww = (j >> 1) == 0 ? mwi[r].x
                    : (j >> 1) == 1 ? mwi[r].y
                    : (j >> 1) == 2 ? mwi[r].z : mwi[r].w;
        uint32_t m = (ww >> (fr + ((j & 1) << 4))) & 1u;
        float v = acc[i][j][r] * scale + (m ? -1e9f : 0.0f);
        acc[i][j][r] = v;
        rmax[i][r] = fmaxf(rmax[i][r], v);
      }
  }
  for (int i = 0; i < 2; ++i)
    for (int r = 0; r < 4; ++r)
      for (int off = 1; off < 16; off <<= 1)
        rmax[i][r] = fmaxf(rmax[i][r], __shfl_xor(rmax[i][r], off, 64));
  __syncthreads();  // all Ks reads done (protects later Pa overwrite too)
  if (fr == 0)
    for (int i = 0; i < 2; ++i)
      for (int r = 0; r < 4; ++r) red[wave * TQ + i * 16 + qd * 4 + r] = rmax[i][r];
  __syncthreads();
  float gmax[2][4];
  for (int i = 0; i < 2; ++i)
    for (int r = 0; r < 4; ++r) {
      int lr = i * 16 + qd * 4 + r;
      float m = red[lr];
      for (int w = 1; w < 8; ++w) m = fmaxf(m, red[w * TQ + lr]);
      gmax[i][r] = m;
    }
  __syncthreads();

  float rsum[2][4];
  for (int i = 0; i < 2; ++i)
    for (int r = 0; r < 4; ++r) rsum[i][r] = 0.f;
  for (int i = 0; i < 2; ++i)
    for (int j = 0; j < 8; ++j)
      for (int r = 0; r < 4; ++r) {
        float e = __expf(acc[i][j][r] - gmax[i][r]);
        acc[i][j][r] = e;
        rsum[i][r] += e;
      }
  for (int i = 0; i < 2; ++i)
    for (int r = 0; r < 4; ++r)
      for (int off = 1; off < 16; off <<= 1)
        rsum[i][r] += __shfl_xor(rsum[i][r], off, 64);
  if (fr == 0)
    for (int i = 0; i < 2; ++i)
      for (int r = 0; r < 4; ++r) red[wave * TQ + i * 16 + qd * 4 + r] = rsum[i][r];
  __syncthreads();

  // ---- phase 2a: normalize -> fp16 -> Pa (A-operand layout, 64-col chunks) ----
  // Pa element (row lr, col) at: (col>>6)*PA_C64 + lr*72 + (col&63)
  for (int i = 0; i < 2; ++i)
    for (int r = 0; r < 4; ++r) {
      int lr = i * 16 + qd * 4 + r;
      float tot = 0.f;
      for (int w = 0; w < 8; ++w) tot += red[w * TQ + lr];
      float inv = 1.0f / tot;
#pragma unroll
      for (int j = 0; j < 8; ++j) {
        int c64 = wave * 2 + (j >> 2);
        int coff = ((j & 3) << 4) + fr;
        Pa[c64 * PA_C64 + lr * 72 + coff] = f2h(acc[i][j][r] * inv);
      }
    }
  __syncthreads();  // Pa complete; all waves may now read any of it

  // ---- write attn (fp32) coalesced from Pa ----
  {
    int row = tid >> 4, p = tid & 15;  // 32 rows x 16 threads
    float* ab = attn + (size_t)bh * (SEQ * (size_t)SEQ) + (size_t)(q0 + row) * SEQ;
#pragma unroll
    for (int u = 0; u < 16; ++u) {
      const h16* src = Pa + u * PA_C64 + row * 72 + p * 4;
      h16x4 hv = *(const h16x4*)src;
      float4 f = { (float)hv[0], (float)hv[1], (float)hv[2], (float)hv[3] };
      *(float4*)(ab + u * 64 + p * 4) = f;
    }
  }

  // ---- phase 2b: PV. ctx_tile[32 q x 512 d] = P[32x1024] @ V_bh; wave owns 64 d ----
  const int d0 = wave * 64;
  const h16* Vb = Vtg + (size_t)bh * (DEP * (size_t)SEQ);
  f32x4 acc2[2][4];
  for (int i = 0; i < 2; ++i)
    for (int j = 0; j < 4; ++j) acc2[i][j] = (f32x4)0.0f;

  h16x8 bfn[4];
#pragma unroll
  for (int j = 0; j < 4; ++j)
    bfn[j] = *(const h16x8*)(Vb + (size_t)(d0 + j * 16 + fr) * SEQ + qd * 8);
  for (int c2 = 0; c2 < 32; ++c2) {
    h16x8 bf[4];
#pragma unroll
    for (int j = 0; j < 4; ++j) bf[j] = bfn[j];
    if (c2 < 31) {
#pragma unroll
      for (int j = 0; j < 4; ++j)
        bfn[j] = *(const h16x8*)(Vb + (size_t)(d0 + j * 16 + fr) * SEQ + (c2 + 1) * 32 + qd * 8);
    }
    h16x8 af2[2];
#pragma unroll
    for (int i = 0; i < 2; ++i)
      af2[i] = *(const h16x8*)(Pa + (c2 >> 1) * PA_C64 + (i * 16 + fr) * 72 + (c2 & 1) * 32 + qd * 8);
    for (int i = 0; i < 2; ++i)
      for (int j = 0; j < 4; ++j) acc2[i][j] = MFMA16(af2[i], bf[j], acc2[i][j]);
  }

  // ---- ctx epilogue: regs -> Cs -> coalesced global (ctx aliases Q tile of THIS block) ----
  __syncthreads();  // all Pa reads done before Cs overwrite
  for (int i = 0; i < 2; ++i)
    for (int j = 0; j < 4; ++j)
      for (int r = 0; r < 4; ++r)
        Cs[(i * 16 + qd * 4 + r) * CS_LD + d0 + j * 16 + fr] = f2h(acc2[i][j][r]);
  __syncthreads();
  {
    int row = tid >> 4, p = tid & 15;
    h16* cg = ctx + (size_t)(b * SEQ + q0 + row) * HD + hh * DEP;
#pragma unroll
    for (int u = 0; u < 4; ++u)
      *(h16x8*)(cg + u * 128 + p * 8) = *(const h16x8*)(Cs + row * CS_LD + u * 128 + p * 8);
  }
}

extern "C" void kernel_launch(void* const* d_in, const int* in_sizes, int n_in,
                              void* d_out, int out_size, void* d_ws, size_t ws_size,
                              hipStream_t stream) {
  const float* v_ip = (const float*)d_in[0];
  const float* k_ip = (const float*)d_in[1];
  const float* q_ip = (const float*)d_in[2];
  const float* mask = (const float*)d_in[3];
  const float* wq = (const float*)d_in[4];
  const float* bq = (const float*)d_in[5];
  const float* wk = (const float*)d_in[6];
  const float* bk = (const float*)d_in[7];
  const float* wv = (const float*)d_in[8];
  const float* bv = (const float*)d_in[9];
  const float* wo = (const float*)d_in[10];
  const float* bo = (const float*)d_in[11];

  char* ws = (char*)d_ws;
  h16* Qh  = (h16*)(ws + (size_t)0);          // 64 MB; per-block overwritten by ctx
  h16* Kh  = (h16*)(ws + (size_t)67108864);   // 64 MB
  h16* Vt  = (h16*)(ws + (size_t)134217728);  // 64 MB, layout (B,H,D,S)
  h16* xq  = (h16*)(ws + (size_t)201326592);  // 8 MB each; xq reused as bits after qkv
  h16* xk  = (h16*)(ws + (size_t)209715200);
  h16* xv  = (h16*)(ws + (size_t)218103808);
  h16* WqT = (h16*)(ws + (size_t)226492416);  // 4 MB each
  h16* WkT = (h16*)(ws + (size_t)230686720);
  h16* WvT = (h16*)(ws + (size_t)234881024);
  h16* WoT = (h16*)(ws + (size_t)239075328);
  uint32_t* bits = (uint32_t*)xq;             // 1 MB (262144 words), written after qkv
  h16* ctx = Qh;

  float* out = (float*)d_out;
  float* attn = out + (size_t)BS * DEP;

  hipFuncSetAttribute((const void*)k_attn,
                      hipFuncAttributeMaxDynamicSharedMemorySize, SMEM_ATTN);

  k_conv3<<<dim3(4096, 3), 256, 0, stream>>>(q_ip, k_ip, v_ip, xq, xk, xv);
  k_transpose3<<<dim3(128, 16, 3), 256, 0, stream>>>(wq, wk, wv, WqT, WkT, WvT);
  k_transpose<<<dim3(16, 128), 256, 0, stream>>>(wo, WoT, 4096, 512);
  k_gemm_qkv<<<dim3(32, 64, 3), 256, 0, stream>>>(xq, xk, xv, WqT, WkT, WvT,
                                                  bq, bk, bv, Qh, Kh, Vt);
  // mask bits: B*S*S/32 = 262,144 words -> 1024 blocks x 256 threads
  k_maskbits<<<1024, 256, 0, stream>>>(mask, bits);
  k_attn<<<dim3(SEQ / TQ, NH, NB), 512, SMEM_ATTN, stream>>>(Qh, Kh, bits, Vt, attn, ctx);
  k_gemm_nt<2><<<dim3(4, 64), 256, 0, stream>>>(ctx, WoT, bo, out, 8192, 512, 4096, 512);
}